// Round 15
// baseline (168.183 us; speedup 1.0000x reference)
//
#include <hip/hip_runtime.h>
#include <cstdint>
#include <cstddef>

#define N_ROWS   65536
#define D_IN     512
#define D_OUT    512
#define N_WORDS  256
#define N_BOOKS  8
#define TAU      5.0f
#define LOG2E    1.44269504088896340736f

typedef __attribute__((ext_vector_type(8))) short short8;
typedef __attribute__((ext_vector_type(4))) float f32x4;

// hardware bf16 convert (RNE)
__device__ __forceinline__ unsigned short f2bf(float f) {
    __bf16 h = (__bf16)f;
    return __builtin_bit_cast(unsigned short, h);
}
__device__ __forceinline__ float bf2f(unsigned short h) {
    unsigned u = ((unsigned)h) << 16;
    return __builtin_bit_cast(float, u);
}

// ============ Kernel 0: pre-pack codebook + W into MFMA fragment order ============
// packA [b][ks(2)][mf(16)][lane(64)][i(8)] : A-frag for xc GEMM (row=m, k=feature)
// packB [b][ks2(8)][n2(4)][lane(64)][i(8)] : B-frag for Z GEMM, m-order matching the
//   NATIVE xc accumulator layout: k-slot (hi=l>>4, i, ks2) -> m = 32*ks2+16*(i>>2)+4*hi+(i&3)
// packW [bn(4)][kk(16)][cf(8)][lane(64)][i(8)] : B-frag for fc GEMM
//   lane l, elem i -> W[bn*128 + cf*16 + (l&15)][kk*32 + (l>>4)*8 + i]
// nc2  [b][m] = -TAU*LOG2E * sum_l bf16(Cb[m][l])^2   (log2-domain bias)
__global__ __launch_bounds__(256) void prep_codebook(
        const float* __restrict__ C, const float* __restrict__ W,
        unsigned short* __restrict__ packA, unsigned short* __restrict__ packB,
        unsigned short* __restrict__ packW, float* __restrict__ nc2) {
    const int gid = blockIdx.x * 256 + threadIdx.x;
    if (gid < 131072) {                       // packA
        const int i  = gid & 7;
        const int l  = (gid >> 3) & 63;
        const int mf = (gid >> 9) & 15;
        const int ks = (gid >> 13) & 1;
        const int b  = gid >> 14;
        const int row = (l & 15) + 16 * mf;                   // m
        const int col = b * 64 + (l >> 4) * 8 + i + 32 * ks;  // feature within C row
        packA[gid] = f2bf(C[(size_t)row * D_IN + col]);
    } else if (gid < 262144) {                // packB (acc-native m-order)
        const int g   = gid - 131072;
        const int i   = g & 7;
        const int l   = (g >> 3) & 63;
        const int n2  = (g >> 9) & 3;
        const int ks2 = (g >> 11) & 7;
        const int b   = g >> 14;
        const int m   = 32 * ks2 + 16 * (i >> 2) + 4 * (l >> 4) + (i & 3);
        const int col = b * 64 + n2 * 16 + (l & 15);
        packB[g] = f2bf(C[(size_t)m * D_IN + col]);
    } else if (gid < 524288) {                // packW
        const int h  = gid - 262144;
        const int i  = h & 7;
        const int l  = (h >> 3) & 63;
        const int cf = (h >> 9) & 7;
        const int kk = (h >> 12) & 15;
        const int bn = h >> 16;
        packW[h] = f2bf(W[(size_t)(bn * 128 + cf * 16 + (l & 15)) * D_IN
                          + kk * 32 + (l >> 4) * 8 + i]);
    } else if (gid < 526336) {                // nc2
        const int t = gid - 524288;
        const int b = t >> 8, m = t & 255;
        const float* cp = C + (size_t)m * D_IN + b * 64;
        float s = 0.f;
        for (int l = 0; l < 64; ++l) {
            const float v = bf2f(f2bf(cp[l]));
            s = fmaf(v, v, s);
        }
        nc2[t] = -TAU * LOG2E * s;
    }
}

// ============ Kernel 1: FUSED fc + quant — 64 rows x 512 cols, wave = one book ============
// fc: x staged in LDS (1-barrier dbuf, 2-deep global prefetch, FULLY UNROLLED K-loop
// so all pipeline regs are statically indexed — rule #20); W-frags wave-private from
// packW (L2). Wave w's acc = X[64 rows][book w]. Per 32-row half: epilogue writes
// X->HBM (NT) + bf16->wave-private LDS bounce, then barrier-free quant (qa[2][16],
// cfr shared across granules, in-lane exp2 softmax, acc-native packB, NT Z stores).
// __launch_bounds__(512, 1): empirically (r10/r13/r14) the 2nd arg acts as CUDA's
// minBlocksPerMultiprocessor on this toolchain — (512,2) capped VGPR at 128 and
// spilled qa (150 MB of scratch-eviction writes). (512,1) permits ~256 VGPRs;
// the ~220-reg live set then fits with zero spill.
__global__ __launch_bounds__(512, 1) void fused_fc_quant(
        const float* __restrict__ x, const unsigned short* __restrict__ packW,
        const float* __restrict__ bias,
        const unsigned short* __restrict__ packA,
        const unsigned short* __restrict__ packB,
        const float* __restrict__ nc2g,
        float* __restrict__ X, float* __restrict__ Z) {
    __shared__ unsigned short Asm[2][64 * 40];                 // 2 x 5 KB x-staging
    __shared__ __attribute__((aligned(16))) unsigned short Xb[8][32 * 72]; // 36 KB bounce
    __shared__ float nc2s[2048];                               // 8 KB, all books

    const int tid  = threadIdx.x;
    const int n0   = blockIdx.x * 64;
    const int lane = tid & 63;
    const int w    = tid >> 6;           // wave = book
    const int lo = lane & 15, hi = lane >> 4;
    const int bn  = w >> 1;              // packW col-block
    const int wc4 = (w & 1) * 4;         // cf offset within bn

    const int row_s = tid >> 3;          // staging row 0..63
    const int fq    = (tid & 7) << 2;    // staging k-offset (floats)

    // ---- stage nc2 (all books) ----
    reinterpret_cast<float4*>(nc2s)[tid] = reinterpret_cast<const float4*>(nc2g)[tid];

    // ---- bias for this wave's book ----
    float biasv[4];
    #pragma unroll
    for (int cf = 0; cf < 4; ++cf) biasv[cf] = bias[w * 64 + cf * 16 + lo];

    // ================= fc phase =================
    f32x4 acc[4][4];   // [fm: rows fm*16+hi*4+j][cf: cols cf*16+lo of book w]
    #pragma unroll
    for (int i = 0; i < 4; ++i)
        #pragma unroll
        for (int j = 0; j < 4; ++j) acc[i][j] = (f32x4){0.f, 0.f, 0.f, 0.f};

    float4 rx[2];
    short8 rw[2][4];
    // prologue: load step 0, stage it, load step 1
    rx[0] = *reinterpret_cast<const float4*>(&x[(size_t)(n0 + row_s) * D_IN + fq]);
    #pragma unroll
    for (int cf = 0; cf < 4; ++cf)
        rw[0][cf] = *reinterpret_cast<const short8*>(
            packW + ((size_t)((bn * 16 + 0) * 8 + wc4 + cf) * 64 + lane) * 8);
    {
        ushort4 p;
        p.x = f2bf(rx[0].x); p.y = f2bf(rx[0].y);
        p.z = f2bf(rx[0].z); p.w = f2bf(rx[0].w);
        *reinterpret_cast<ushort4*>(&Asm[0][row_s * 40 + fq]) = p;
    }
    rx[1] = *reinterpret_cast<const float4*>(&x[(size_t)(n0 + row_s) * D_IN + 32 + fq]);
    #pragma unroll
    for (int cf = 0; cf < 4; ++cf)
        rw[1][cf] = *reinterpret_cast<const short8*>(
            packW + ((size_t)((bn * 16 + 1) * 8 + wc4 + cf) * 64 + lane) * 8);
    __syncthreads();

    #pragma unroll
    for (int kk = 0; kk < 16; ++kk) {   // FULL unroll: all rx/rw indices static
        const int cur = kk & 1;
        short8 aW[4];
        #pragma unroll
        for (int cf = 0; cf < 4; ++cf) aW[cf] = rw[cur][cf];
        // issue loads for step kk+2 (2-deep pipeline)
        if (kk < 14) {
            rx[cur] = *reinterpret_cast<const float4*>(
                &x[(size_t)(n0 + row_s) * D_IN + (kk + 2) * 32 + fq]);
            #pragma unroll
            for (int cf = 0; cf < 4; ++cf)
                rw[cur][cf] = *reinterpret_cast<const short8*>(
                    packW + ((size_t)((bn * 16 + kk + 2) * 8 + wc4 + cf) * 64 + lane) * 8);
        }
        // compute on buf[cur]
        short8 a[4];
        #pragma unroll
        for (int fm = 0; fm < 4; ++fm)
            a[fm] = *reinterpret_cast<const short8*>(&Asm[cur][(fm * 16 + lo) * 40 + hi * 8]);
        #pragma unroll
        for (int fm = 0; fm < 4; ++fm)
            #pragma unroll
            for (int cf = 0; cf < 4; ++cf)
                acc[fm][cf] = __builtin_amdgcn_mfma_f32_16x16x32_bf16(
                    a[fm], aW[cf], acc[fm][cf], 0, 0, 0);
        // stage step kk+1 into buf[cur^1] (vmcnt wait lands after the MFMAs)
        if (kk < 15) {
            const float4 v = rx[cur ^ 1];
            ushort4 p;
            p.x = f2bf(v.x); p.y = f2bf(v.y); p.z = f2bf(v.z); p.w = f2bf(v.w);
            *reinterpret_cast<ushort4*>(&Asm[cur ^ 1][row_s * 40 + fq]) = p;
            __syncthreads();
        }
    }

    // ================= per-half epilogue + quant (barrier-free) =================
    const float S2 = 2.0f * TAU * LOG2E;
    #pragma unroll
    for (int h = 0; h < 2; ++h) {
        // ---- epilogue: bias, X -> HBM (NT; never re-read), bf16 -> bounce ----
        #pragma unroll
        for (int fmh = 0; fmh < 2; ++fmh) {
            const int fm = h * 2 + fmh;
            #pragma unroll
            for (int cf = 0; cf < 4; ++cf)
                #pragma unroll
                for (int j = 0; j < 4; ++j) {
                    const float v = acc[fm][cf][j] + biasv[cf];
                    __builtin_nontemporal_store(
                        v, &X[(size_t)(n0 + h * 32 + fmh * 16 + hi * 4 + j) * D_OUT
                              + w * 64 + cf * 16 + lo]);
                    Xb[w][(fmh * 16 + hi * 4 + j) * 72 + cf * 16 + lo] = f2bf(v);
                }
        }
        asm volatile("s_waitcnt lgkmcnt(0)" ::: "memory");

        // ---- xf frags for the 2 granules (16 rows each) ----
        short8 xf[2][2];
        #pragma unroll
        for (int g = 0; g < 2; ++g)
            #pragma unroll
            for (int ks = 0; ks < 2; ++ks)
                xf[g][ks] = *reinterpret_cast<const short8*>(
                    &Xb[w][(g * 16 + lo) * 72 + ks * 32 + hi * 8]);

        // ---- xc MFMA: 32 rows x 256 m, cfr shared across granules ----
        f32x4 qa[2][16];
        #pragma unroll
        for (int g = 0; g < 2; ++g)
            #pragma unroll
            for (int mf = 0; mf < 16; ++mf) qa[g][mf] = (f32x4){0.f, 0.f, 0.f, 0.f};
        #pragma unroll
        for (int ks = 0; ks < 2; ++ks)
            #pragma unroll
            for (int mf = 0; mf < 16; ++mf) {
                const short8 cfr = *reinterpret_cast<const short8*>(
                    packA + ((size_t)((w * 2 + ks) * 16 + mf) * 64 + lane) * 8);
                qa[0][mf] = __builtin_amdgcn_mfma_f32_16x16x32_bf16(cfr, xf[0][ks], qa[0][mf], 0, 0, 0);
                qa[1][mf] = __builtin_amdgcn_mfma_f32_16x16x32_bf16(cfr, xf[1][ks], qa[1][mf], 0, 0, 0);
            }

        // ---- softmax (exp2 domain, in-lane, unnormalized p kept in qa) ----
        float inv[2];
        #pragma unroll
        for (int g = 0; g < 2; ++g) {
            float s = 0.f;
            #pragma unroll
            for (int mf = 0; mf < 16; ++mf) {
                const f32x4 nv = *reinterpret_cast<const f32x4*>(
                    &nc2s[w * 256 + mf * 16 + hi * 4]);
                const float p0 = exp2f(fmaf(qa[g][mf][0], S2, nv[0]));
                const float p1 = exp2f(fmaf(qa[g][mf][1], S2, nv[1]));
                const float p2 = exp2f(fmaf(qa[g][mf][2], S2, nv[2]));
                const float p3 = exp2f(fmaf(qa[g][mf][3], S2, nv[3]));
                qa[g][mf][0] = p0; qa[g][mf][1] = p1;
                qa[g][mf][2] = p2; qa[g][mf][3] = p3;
                s += (p0 + p1) + (p2 + p3);
            }
            s += __shfl_xor(s, 16, 64);
            s += __shfl_xor(s, 32, 64);
            inv[g] = 1.0f / s;
        }

        // ---- Z = p @ Cb : pa in-lane (packB m-order == qa layout), bv shared ----
        f32x4 acc2[2][4];
        #pragma unroll
        for (int g = 0; g < 2; ++g)
            #pragma unroll
            for (int n2 = 0; n2 < 4; ++n2) acc2[g][n2] = (f32x4){0.f, 0.f, 0.f, 0.f};
        #pragma unroll
        for (int ks2 = 0; ks2 < 8; ++ks2) {
            short8 pa[2];
            #pragma unroll
            for (int g = 0; g < 2; ++g) {
                pa[g][0] = (short)f2bf(qa[g][2 * ks2][0]);
                pa[g][1] = (short)f2bf(qa[g][2 * ks2][1]);
                pa[g][2] = (short)f2bf(qa[g][2 * ks2][2]);
                pa[g][3] = (short)f2bf(qa[g][2 * ks2][3]);
                pa[g][4] = (short)f2bf(qa[g][2 * ks2 + 1][0]);
                pa[g][5] = (short)f2bf(qa[g][2 * ks2 + 1][1]);
                pa[g][6] = (short)f2bf(qa[g][2 * ks2 + 1][2]);
                pa[g][7] = (short)f2bf(qa[g][2 * ks2 + 1][3]);
            }
            #pragma unroll
            for (int n2 = 0; n2 < 4; ++n2) {
                const short8 bv = *reinterpret_cast<const short8*>(
                    packB + ((size_t)((w * 8 + ks2) * 4 + n2) * 64 + lane) * 8);
                acc2[0][n2] = __builtin_amdgcn_mfma_f32_16x16x32_bf16(pa[0], bv, acc2[0][n2], 0, 0, 0);
                acc2[1][n2] = __builtin_amdgcn_mfma_f32_16x16x32_bf16(pa[1], bv, acc2[1][n2], 0, 0, 0);
            }
        }

        #pragma unroll
        for (int g = 0; g < 2; ++g) {
            float invr[4];
            #pragma unroll
            for (int j = 0; j < 4; ++j) invr[j] = __shfl(inv[g], hi * 4 + j, 64);
            #pragma unroll
            for (int n2 = 0; n2 < 4; ++n2)
                #pragma unroll
                for (int j = 0; j < 4; ++j)
                    __builtin_nontemporal_store(
                        acc2[g][n2][j] * invr[j],
                        &Z[(size_t)(n0 + h * 32 + g * 16 + hi * 4 + j) * D_OUT
                           + w * 64 + n2 * 16 + lo]);
        }
    }
}

// ============ launch ============
extern "C" void kernel_launch(void* const* d_in, const int* in_sizes, int n_in,
                              void* d_out, int out_size, void* d_ws, size_t ws_size,
                              hipStream_t stream) {
    const float* x = (const float*)d_in[0];
    const float* W = (const float*)d_in[1];
    const float* b = (const float*)d_in[2];
    const float* C = (const float*)d_in[3];

    float* X = (float*)d_out;                      // output 0: [65536, 512]
    float* Z = X + (size_t)N_ROWS * D_OUT;         // output 1: [65536, 512]

    unsigned short* packA = (unsigned short*)d_ws;          // 131072 bf16 = 256 KB
    unsigned short* packB = packA + 131072;                 // 131072 bf16 = 256 KB
    unsigned short* packW = packB + 131072;                 // 262144 bf16 = 512 KB
    float*          nc2g  = (float*)(packW + 262144);       // 2048 fp32  =   8 KB

    prep_codebook<<<dim3(2056), dim3(256), 0, stream>>>(C, W, packA, packB, packW, nc2g);
    fused_fc_quant<<<dim3(N_ROWS / 64), dim3(512), 0, stream>>>(
        x, packW, b, packA, packB, nc2g, X, Z);
}

// Round 17
// 159.408 us; speedup vs baseline: 1.0550x; 1.0550x over previous
//
#include <hip/hip_runtime.h>
#include <cstdint>
#include <cstddef>

#define N_ROWS   65536
#define D_IN     512
#define D_OUT    512
#define N_WORDS  256
#define N_BOOKS  8
#define TAU      5.0f
#define LOG2E    1.44269504088896340736f

typedef __attribute__((ext_vector_type(8))) short short8;
typedef __attribute__((ext_vector_type(4))) float f32x4;

// hardware bf16 convert (RNE) — native __bf16 lets the compiler pair into v_cvt_pk_bf16_f32
__device__ __forceinline__ unsigned short f2bf(float f) {
    __bf16 h = (__bf16)f;
    return __builtin_bit_cast(unsigned short, h);
}
__device__ __forceinline__ float bf2f(unsigned short h) {
    unsigned u = ((unsigned)h) << 16;
    return __builtin_bit_cast(float, u);
}

// ============ Kernel 0: pre-pack codebook + W into MFMA fragment order ============
// packA [b][ks(2)][mf(16)][lane(64)][i(8)] : A-frag for xc GEMM (row=m, k=feature)
// packB [b][ks2(8)][n2(4)][lane(64)][i(8)] : B-frag for Z GEMM, m-order matching the
//   NATIVE xc accumulator layout: k-slot (hi=l>>4, i, ks2) -> m = 32*ks2+16*(i>>2)+4*hi+(i&3)
// packW [bn(4)][kk(16)][cf(8)][lane(64)][i(8)] : B-frag for fc GEMM
//   lane l, elem i -> W[bn*128 + cf*16 + (l&15)][kk*32 + (l>>4)*8 + i]
// nc2  [b][m] = -TAU*LOG2E * sum_l bf16(Cb[m][l])^2   (log2-domain bias)
__global__ __launch_bounds__(256) void prep_codebook(
        const float* __restrict__ C, const float* __restrict__ W,
        unsigned short* __restrict__ packA, unsigned short* __restrict__ packB,
        unsigned short* __restrict__ packW, float* __restrict__ nc2) {
    const int gid = blockIdx.x * 256 + threadIdx.x;
    if (gid < 131072) {                       // packA
        const int i  = gid & 7;
        const int l  = (gid >> 3) & 63;
        const int mf = (gid >> 9) & 15;
        const int ks = (gid >> 13) & 1;
        const int b  = gid >> 14;
        const int row = (l & 15) + 16 * mf;                   // m
        const int col = b * 64 + (l >> 4) * 8 + i + 32 * ks;  // feature within C row
        packA[gid] = f2bf(C[(size_t)row * D_IN + col]);
    } else if (gid < 262144) {                // packB (acc-native m-order)
        const int g   = gid - 131072;
        const int i   = g & 7;
        const int l   = (g >> 3) & 63;
        const int n2  = (g >> 9) & 3;
        const int ks2 = (g >> 11) & 7;
        const int b   = g >> 14;
        const int m   = 32 * ks2 + 16 * (i >> 2) + 4 * (l >> 4) + (i & 3);
        const int col = b * 64 + n2 * 16 + (l & 15);
        packB[g] = f2bf(C[(size_t)m * D_IN + col]);
    } else if (gid < 524288) {                // packW
        const int h  = gid - 262144;
        const int i  = h & 7;
        const int l  = (h >> 3) & 63;
        const int cf = (h >> 9) & 7;
        const int kk = (h >> 12) & 15;
        const int bn = h >> 16;
        packW[h] = f2bf(W[(size_t)(bn * 128 + cf * 16 + (l & 15)) * D_IN
                          + kk * 32 + (l >> 4) * 8 + i]);
    } else if (gid < 526336) {                // nc2
        const int t = gid - 524288;
        const int b = t >> 8, m = t & 255;
        const float* cp = C + (size_t)m * D_IN + b * 64;
        float s = 0.f;
        for (int l = 0; l < 64; ++l) {
            const float v = bf2f(f2bf(cp[l]));
            s = fmaf(v, v, s);
        }
        nc2[t] = -TAU * LOG2E * s;
    }
}

// ============ Kernel 1: X = x @ W^T + b  (bf16 MFMA, BM=256, double-buffered) ============
// One barrier per K-step: {issue loads k+1} -> {ds_read + MFMA on buf[cur]} ->
// {vmcnt-wait, cvt, ds_write buf[cur^1]} -> {barrier}.
// X stores are NON-TEMPORAL: X is re-read only by the NEXT kernel (128 MB >> 32 MB L2,
// so caching buys nothing) while cached stores evict the x rows that co-XCD sibling
// blocks re-read — same mechanism as the r12 NT-Z win (-14 us).
#define ASTR 40   // x-staging LDS row stride in bf16 elems (80 B)

__global__ __launch_bounds__(512, 4) void gemm_fc(
        const float* __restrict__ x, const unsigned short* __restrict__ packW,
        const float* __restrict__ bias, float* __restrict__ X) {
    __shared__ unsigned short Asm[2][256 * ASTR];                      // 2 x 20 KB
    __shared__ __attribute__((aligned(16))) unsigned short Wsm[2][4096]; // 2 x 8 KB

    const int tid = threadIdx.x;
    const int bid = blockIdx.x;
    // co-XCD grouping: the 4 bn-tiles of one bm sit consecutively on ONE XCD
    const int xcd = bid & 7;
    const int idx = bid >> 3;            // 0..127 per XCD
    const int bm  = xcd * 32 + (idx >> 2);
    const int bn  = idx & 3;
    const int n0 = bm * 256, c0 = bn * 128;
    const int lane = tid & 63, w = tid >> 6;
    const int wr = w >> 1, wc = w & 1;   // wave grid 4 x 2
    const int lo = lane & 15, hi = lane >> 4;

    const int sr = tid >> 1;             // staging row 0..255 (2 threads/row)
    const int sf = (tid & 1) << 4;       // k-offset 0 or 16 floats

    f32x4 acc[4][4];                     // rows wr*64+fm*16+..., cols wc*64+cf*16+lo
    #pragma unroll
    for (int i = 0; i < 4; ++i)
        #pragma unroll
        for (int j = 0; j < 4; ++j) acc[i][j] = (f32x4){0.f, 0.f, 0.f, 0.f};

    const float4* gW = reinterpret_cast<const float4*>(packW);

    // ---- prologue: load + stage K-step 0 into buffer 0 ----
    float4 ra[4];
    float4 rw;
    {
        const float* xa = &x[(size_t)(n0 + sr) * D_IN + sf];
        #pragma unroll
        for (int q = 0; q < 4; ++q)
            ra[q] = *reinterpret_cast<const float4*>(xa + q * 4);
        rw = gW[(size_t)(bn * 16) * 512 + tid];
    }
    #pragma unroll
    for (int q = 0; q < 4; ++q) {
        ushort4 pa;
        pa.x = f2bf(ra[q].x); pa.y = f2bf(ra[q].y);
        pa.z = f2bf(ra[q].z); pa.w = f2bf(ra[q].w);
        *reinterpret_cast<ushort4*>(&Asm[0][sr * ASTR + sf + q * 4]) = pa;
    }
    *reinterpret_cast<float4*>(&Wsm[0][tid * 8]) = rw;
    __syncthreads();

    for (int kk = 0; kk < 16; ++kk) {
        const int cur = kk & 1;
        // issue next step's global loads (completion awaited only after the MFMAs)
        if (kk < 15) {
            const float* xa = &x[(size_t)(n0 + sr) * D_IN + (kk + 1) * 32 + sf];
            #pragma unroll
            for (int q = 0; q < 4; ++q)
                ra[q] = *reinterpret_cast<const float4*>(xa + q * 4);
            rw = gW[(size_t)(bn * 16 + kk + 1) * 512 + tid];
        }
        // compute on buf[cur]
        short8 a[4], bb[4];
        #pragma unroll
        for (int fm = 0; fm < 4; ++fm)
            a[fm] = *reinterpret_cast<const short8*>(
                &Asm[cur][(wr * 64 + fm * 16 + lo) * ASTR + hi * 8]);
        #pragma unroll
        for (int cf = 0; cf < 4; ++cf)
            bb[cf] = *reinterpret_cast<const short8*>(
                &Wsm[cur][((wc * 4 + cf) * 64 + lane) * 8]);
        #pragma unroll
        for (int fm = 0; fm < 4; ++fm)
            #pragma unroll
            for (int cf = 0; cf < 4; ++cf)
                acc[fm][cf] = __builtin_amdgcn_mfma_f32_16x16x32_bf16(
                    a[fm], bb[cf], acc[fm][cf], 0, 0, 0);
        // stage next step into buf[cur^1] (vmcnt wait happens here, after MFMAs)
        if (kk < 15) {
            #pragma unroll
            for (int q = 0; q < 4; ++q) {
                ushort4 pa;
                pa.x = f2bf(ra[q].x); pa.y = f2bf(ra[q].y);
                pa.z = f2bf(ra[q].z); pa.w = f2bf(ra[q].w);
                *reinterpret_cast<ushort4*>(&Asm[cur ^ 1][sr * ASTR + sf + q * 4]) = pa;
            }
            *reinterpret_cast<float4*>(&Wsm[cur ^ 1][tid * 8]) = rw;
            __syncthreads();
        }
    }

    #pragma unroll
    for (int cf = 0; cf < 4; ++cf) {
        const float bv = bias[c0 + wc * 64 + cf * 16 + lo];
        #pragma unroll
        for (int fm = 0; fm < 4; ++fm)
            #pragma unroll
            for (int j = 0; j < 4; ++j)
                __builtin_nontemporal_store(
                    acc[fm][cf][j] + bv,
                    &X[(size_t)(n0 + wr * 64 + fm * 16 + hi * 4 + j) * D_OUT
                       + c0 + wc * 64 + cf * 16 + lo]);
    }
}

// ============ Kernel 2: soft quantization head — 256 rows/block, in-register pa ============
// Block = (book b, 256 rows), 512 threads; wave w: rows w*32..+31 in 2 x 16-row iters
// vs ALL 256 m. xc = mfma(Cb, X^T): lane (lo,hi) holds p[x-row lo][m=16*mf+4*hi+j].
// Z GEMM's pa built IN-LANE from qa (packB m-order == qa layout). One barrier.
// X loads issued upfront (NT hint via ext-vector f32x4 — __builtin_nontemporal_load
// rejects HIP_vector_type float4) and RETIRED into xf before the MFMA region
// (peak live set ~100 VGPR — no spill). Z stores non-temporal (r12, -14 us).
__global__ __launch_bounds__(512, 4) void quant_head(
        const float* __restrict__ X, const unsigned short* __restrict__ packA,
        const unsigned short* __restrict__ packB, const float* __restrict__ nc2g,
        float* __restrict__ Z) {
    __shared__ __attribute__((aligned(16))) unsigned short cbA[16384];
    __shared__ __attribute__((aligned(16))) unsigned short cbB[16384];
    __shared__ float nc2s[256];

    const int tid  = threadIdx.x;
    const int bid  = blockIdx.x;
    // co-XCD grouping: 8 books of the same row range sit consecutively on ONE XCD
    const int xcd = bid & 7;
    const int idx = bid >> 3;            // 0..255 per XCD
    const int b   = idx & 7;
    const int n0  = (xcd * 32 + (idx >> 3)) * 256;
    const int lane = tid & 63;
    const int w    = tid >> 6;
    const int lo = lane & 15, hi = lane >> 4;

    // ---- X loads for both halves first (HBM latency starts earliest; NT hint) ----
    f32x4 rx[2][4];
    #pragma unroll
    for (int h = 0; h < 2; ++h) {
        const float* xp = X + (size_t)(n0 + w * 32 + h * 16 + lo) * D_OUT + b * 64 + hi * 8;
        rx[h][0] = __builtin_nontemporal_load(reinterpret_cast<const f32x4*>(xp));
        rx[h][1] = __builtin_nontemporal_load(reinterpret_cast<const f32x4*>(xp + 4));
        rx[h][2] = __builtin_nontemporal_load(reinterpret_cast<const f32x4*>(xp + 32));
        rx[h][3] = __builtin_nontemporal_load(reinterpret_cast<const f32x4*>(xp + 36));
    }

    // ---- stage codebook frags + nc2 into LDS ----
    {
        const float4* gA = reinterpret_cast<const float4*>(packA + (size_t)b * 16384);
        const float4* gB = reinterpret_cast<const float4*>(packB + (size_t)b * 16384);
        float4* sA = reinterpret_cast<float4*>(cbA);
        float4* sB = reinterpret_cast<float4*>(cbB);
        #pragma unroll
        for (int it = 0; it < 4; ++it) {
            sA[it * 512 + tid] = gA[it * 512 + tid];
            sB[it * 512 + tid] = gB[it * 512 + tid];
        }
        if (tid < 256) nc2s[tid] = nc2g[b * 256 + tid];
    }

    // ---- convert X to bf16 B-frags while staging lands (retires rx) ----
    short8 xf[2][2];   // [half][ks]
    #pragma unroll
    for (int h = 0; h < 2; ++h)
        #pragma unroll
        for (int ks = 0; ks < 2; ++ks) {
            const f32x4 v0 = rx[h][ks * 2];
            const f32x4 v1 = rx[h][ks * 2 + 1];
            short8 t;
            t[0] = (short)f2bf(v0[0]); t[1] = (short)f2bf(v0[1]);
            t[2] = (short)f2bf(v0[2]); t[3] = (short)f2bf(v0[3]);
            t[4] = (short)f2bf(v1[0]); t[5] = (short)f2bf(v1[1]);
            t[6] = (short)f2bf(v1[2]); t[7] = (short)f2bf(v1[3]);
            xf[h][ks] = t;
        }

    __syncthreads();   // codebook + nc2 staged

    const float S2 = 2.0f * TAU * LOG2E;
    for (int h = 0; h < 2; ++h) {
        // ---- xc MFMA: 16 rows x 256 m ----
        f32x4 qa[16];
        #pragma unroll
        for (int mf = 0; mf < 16; ++mf) qa[mf] = (f32x4){0.f, 0.f, 0.f, 0.f};
        #pragma unroll
        for (int ks = 0; ks < 2; ++ks)
            #pragma unroll
            for (int mf = 0; mf < 16; ++mf) {
                const short8 cfr = *reinterpret_cast<const short8*>(
                    &cbA[((ks * 16 + mf) * 64 + lane) * 8]);
                qa[mf] = __builtin_amdgcn_mfma_f32_16x16x32_bf16(
                    cfr, xf[h][ks], qa[mf], 0, 0, 0);
            }

        // ---- softmax (exp2 domain, in-lane, unnormalized p kept in qa) ----
        float s = 0.f;
        #pragma unroll
        for (int mf = 0; mf < 16; ++mf) {
            const f32x4 nv = *reinterpret_cast<const f32x4*>(&nc2s[mf * 16 + hi * 4]);
            const float p0 = exp2f(fmaf(qa[mf][0], S2, nv[0]));
            const float p1 = exp2f(fmaf(qa[mf][1], S2, nv[1]));
            const float p2 = exp2f(fmaf(qa[mf][2], S2, nv[2]));
            const float p3 = exp2f(fmaf(qa[mf][3], S2, nv[3]));
            qa[mf][0] = p0; qa[mf][1] = p1; qa[mf][2] = p2; qa[mf][3] = p3;
            s += (p0 + p1) + (p2 + p3);
        }
        s += __shfl_xor(s, 16, 64);
        s += __shfl_xor(s, 32, 64);
        const float inv = 1.0f / s;            // full 256-sum for this half's row `lo`

        // ---- Z = p @ Cb : pa built in-lane (packB m-order == qa layout) ----
        f32x4 acc2[4];
        #pragma unroll
        for (int n2 = 0; n2 < 4; ++n2) acc2[n2] = (f32x4){0.f, 0.f, 0.f, 0.f};
        #pragma unroll
        for (int ks2 = 0; ks2 < 8; ++ks2) {
            short8 pa;
            pa[0] = (short)f2bf(qa[2 * ks2][0]);     pa[1] = (short)f2bf(qa[2 * ks2][1]);
            pa[2] = (short)f2bf(qa[2 * ks2][2]);     pa[3] = (short)f2bf(qa[2 * ks2][3]);
            pa[4] = (short)f2bf(qa[2 * ks2 + 1][0]); pa[5] = (short)f2bf(qa[2 * ks2 + 1][1]);
            pa[6] = (short)f2bf(qa[2 * ks2 + 1][2]); pa[7] = (short)f2bf(qa[2 * ks2 + 1][3]);
            #pragma unroll
            for (int n2 = 0; n2 < 4; ++n2) {
                const short8 bv = *reinterpret_cast<const short8*>(
                    &cbB[((ks2 * 4 + n2) * 64 + lane) * 8]);
                acc2[n2] = __builtin_amdgcn_mfma_f32_16x16x32_bf16(pa, bv, acc2[n2], 0, 0, 0);
            }
        }

        float invr[4];
        #pragma unroll
        for (int j = 0; j < 4; ++j) invr[j] = __shfl(inv, hi * 4 + j, 64);
        #pragma unroll
        for (int n2 = 0; n2 < 4; ++n2)
            #pragma unroll
            for (int j = 0; j < 4; ++j)
                __builtin_nontemporal_store(
                    acc2[n2][j] * invr[j],
                    &Z[(size_t)(n0 + w * 32 + h * 16 + hi * 4 + j) * D_OUT
                       + b * 64 + n2 * 16 + lo]);
    }
}

// ============ launch ============
extern "C" void kernel_launch(void* const* d_in, const int* in_sizes, int n_in,
                              void* d_out, int out_size, void* d_ws, size_t ws_size,
                              hipStream_t stream) {
    const float* x = (const float*)d_in[0];
    const float* W = (const float*)d_in[1];
    const float* b = (const float*)d_in[2];
    const float* C = (const float*)d_in[3];

    float* X = (float*)d_out;                      // output 0: [65536, 512]
    float* Z = X + (size_t)N_ROWS * D_OUT;         // output 1: [65536, 512]

    unsigned short* packA = (unsigned short*)d_ws;          // 131072 bf16 = 256 KB
    unsigned short* packB = packA + 131072;                 // 131072 bf16 = 256 KB
    unsigned short* packW = packB + 131072;                 // 262144 bf16 = 512 KB
    float*          nc2g  = (float*)(packW + 262144);       // 2048 fp32  =   8 KB

    prep_codebook<<<dim3(2056), dim3(256), 0, stream>>>(C, W, packA, packB, packW, nc2g);
    gemm_fc<<<dim3(1024), dim3(512), 0, stream>>>(x, packW, b, X);
    quant_head<<<dim3(N_BOOKS * (N_ROWS / 256)), dim3(512), 0, stream>>>(
        X, packA, packB, nc2g, Z);
}

// Round 18
// 148.108 us; speedup vs baseline: 1.1355x; 1.0763x over previous
//
#include <hip/hip_runtime.h>
#include <cstdint>
#include <cstddef>

#define N_ROWS   65536
#define D_IN     512
#define D_OUT    512
#define N_WORDS  256
#define N_BOOKS  8
#define TAU      5.0f
#define LOG2E    1.44269504088896340736f

typedef __attribute__((ext_vector_type(8))) short short8;
typedef __attribute__((ext_vector_type(4))) float f32x4;

// hardware bf16 convert (RNE) — native __bf16 lets the compiler pair into v_cvt_pk_bf16_f32
__device__ __forceinline__ unsigned short f2bf(float f) {
    __bf16 h = (__bf16)f;
    return __builtin_bit_cast(unsigned short, h);
}
__device__ __forceinline__ float bf2f(unsigned short h) {
    unsigned u = ((unsigned)h) << 16;
    return __builtin_bit_cast(float, u);
}

// ============ Kernel 0: pre-pack codebook + W into MFMA fragment order ============
// packA [b][ks(2)][mf(16)][lane(64)][i(8)] : A-frag for xc GEMM (row=m, k=feature)
// packB [b][ks2(8)][n2(4)][lane(64)][i(8)] : B-frag for Z GEMM, m-order matching the
//   NATIVE xc accumulator layout: k-slot (hi=l>>4, i, ks2) -> m = 32*ks2+16*(i>>2)+4*hi+(i&3)
// packW [bn(4)][kk(16)][cf(8)][lane(64)][i(8)] : B-frag for fc GEMM
//   lane l, elem i -> W[bn*128 + cf*16 + (l&15)][kk*32 + (l>>4)*8 + i]
// nc2  [b][m] = -TAU*LOG2E * sum_l bf16(Cb[m][l])^2   (log2-domain bias)
__global__ __launch_bounds__(256) void prep_codebook(
        const float* __restrict__ C, const float* __restrict__ W,
        unsigned short* __restrict__ packA, unsigned short* __restrict__ packB,
        unsigned short* __restrict__ packW, float* __restrict__ nc2) {
    const int gid = blockIdx.x * 256 + threadIdx.x;
    if (gid < 131072) {                       // packA
        const int i  = gid & 7;
        const int l  = (gid >> 3) & 63;
        const int mf = (gid >> 9) & 15;
        const int ks = (gid >> 13) & 1;
        const int b  = gid >> 14;
        const int row = (l & 15) + 16 * mf;                   // m
        const int col = b * 64 + (l >> 4) * 8 + i + 32 * ks;  // feature within C row
        packA[gid] = f2bf(C[(size_t)row * D_IN + col]);
    } else if (gid < 262144) {                // packB (acc-native m-order)
        const int g   = gid - 131072;
        const int i   = g & 7;
        const int l   = (g >> 3) & 63;
        const int n2  = (g >> 9) & 3;
        const int ks2 = (g >> 11) & 7;
        const int b   = g >> 14;
        const int m   = 32 * ks2 + 16 * (i >> 2) + 4 * (l >> 4) + (i & 3);
        const int col = b * 64 + n2 * 16 + (l & 15);
        packB[g] = f2bf(C[(size_t)m * D_IN + col]);
    } else if (gid < 524288) {                // packW
        const int h  = gid - 262144;
        const int i  = h & 7;
        const int l  = (h >> 3) & 63;
        const int cf = (h >> 9) & 7;
        const int kk = (h >> 12) & 15;
        const int bn = h >> 16;
        packW[h] = f2bf(W[(size_t)(bn * 128 + cf * 16 + (l & 15)) * D_IN
                          + kk * 32 + (l >> 4) * 8 + i]);
    } else if (gid < 526336) {                // nc2
        const int t = gid - 524288;
        const int b = t >> 8, m = t & 255;
        const float* cp = C + (size_t)m * D_IN + b * 64;
        float s = 0.f;
        for (int l = 0; l < 64; ++l) {
            const float v = bf2f(f2bf(cp[l]));
            s = fmaf(v, v, s);
        }
        nc2[t] = -TAU * LOG2E * s;
    }
}

// ============ Kernel 1: X = x @ W^T + b  (bf16 MFMA, BM=256, double-buffered) ============
// One barrier per K-step: {issue loads k+1} -> {ds_read + MFMA on buf[cur]} ->
// {vmcnt-wait, cvt, ds_write buf[cur^1]} -> {barrier}.
// X stores are CACHED (r17 lesson): X (128 MB) fits in the 256 MB L3, so cached
// stores make quant_head's re-read an L3 hit; NT X-stores forced it to HBM (+12 us).
#define ASTR 40   // x-staging LDS row stride in bf16 elems (80 B)

__global__ __launch_bounds__(512, 4) void gemm_fc(
        const float* __restrict__ x, const unsigned short* __restrict__ packW,
        const float* __restrict__ bias, float* __restrict__ X) {
    __shared__ unsigned short Asm[2][256 * ASTR];                      // 2 x 20 KB
    __shared__ __attribute__((aligned(16))) unsigned short Wsm[2][4096]; // 2 x 8 KB

    const int tid = threadIdx.x;
    const int bid = blockIdx.x;
    // co-XCD grouping: the 4 bn-tiles of one bm sit consecutively on ONE XCD
    const int xcd = bid & 7;
    const int idx = bid >> 3;            // 0..127 per XCD
    const int bm  = xcd * 32 + (idx >> 2);
    const int bn  = idx & 3;
    const int n0 = bm * 256, c0 = bn * 128;
    const int lane = tid & 63, w = tid >> 6;
    const int wr = w >> 1, wc = w & 1;   // wave grid 4 x 2
    const int lo = lane & 15, hi = lane >> 4;

    const int sr = tid >> 1;             // staging row 0..255 (2 threads/row)
    const int sf = (tid & 1) << 4;       // k-offset 0 or 16 floats

    f32x4 acc[4][4];                     // rows wr*64+fm*16+..., cols wc*64+cf*16+lo
    #pragma unroll
    for (int i = 0; i < 4; ++i)
        #pragma unroll
        for (int j = 0; j < 4; ++j) acc[i][j] = (f32x4){0.f, 0.f, 0.f, 0.f};

    const float4* gW = reinterpret_cast<const float4*>(packW);

    // ---- prologue: load + stage K-step 0 into buffer 0 ----
    float4 ra[4];
    float4 rw;
    {
        const float* xa = &x[(size_t)(n0 + sr) * D_IN + sf];
        #pragma unroll
        for (int q = 0; q < 4; ++q)
            ra[q] = *reinterpret_cast<const float4*>(xa + q * 4);
        rw = gW[(size_t)(bn * 16) * 512 + tid];
    }
    #pragma unroll
    for (int q = 0; q < 4; ++q) {
        ushort4 pa;
        pa.x = f2bf(ra[q].x); pa.y = f2bf(ra[q].y);
        pa.z = f2bf(ra[q].z); pa.w = f2bf(ra[q].w);
        *reinterpret_cast<ushort4*>(&Asm[0][sr * ASTR + sf + q * 4]) = pa;
    }
    *reinterpret_cast<float4*>(&Wsm[0][tid * 8]) = rw;
    __syncthreads();

    for (int kk = 0; kk < 16; ++kk) {
        const int cur = kk & 1;
        // issue next step's global loads (completion awaited only after the MFMAs)
        if (kk < 15) {
            const float* xa = &x[(size_t)(n0 + sr) * D_IN + (kk + 1) * 32 + sf];
            #pragma unroll
            for (int q = 0; q < 4; ++q)
                ra[q] = *reinterpret_cast<const float4*>(xa + q * 4);
            rw = gW[(size_t)(bn * 16 + kk + 1) * 512 + tid];
        }
        // compute on buf[cur]
        short8 a[4], bb[4];
        #pragma unroll
        for (int fm = 0; fm < 4; ++fm)
            a[fm] = *reinterpret_cast<const short8*>(
                &Asm[cur][(wr * 64 + fm * 16 + lo) * ASTR + hi * 8]);
        #pragma unroll
        for (int cf = 0; cf < 4; ++cf)
            bb[cf] = *reinterpret_cast<const short8*>(
                &Wsm[cur][((wc * 4 + cf) * 64 + lane) * 8]);
        #pragma unroll
        for (int fm = 0; fm < 4; ++fm)
            #pragma unroll
            for (int cf = 0; cf < 4; ++cf)
                acc[fm][cf] = __builtin_amdgcn_mfma_f32_16x16x32_bf16(
                    a[fm], bb[cf], acc[fm][cf], 0, 0, 0);
        // stage next step into buf[cur^1] (vmcnt wait happens here, after MFMAs)
        if (kk < 15) {
            #pragma unroll
            for (int q = 0; q < 4; ++q) {
                ushort4 pa;
                pa.x = f2bf(ra[q].x); pa.y = f2bf(ra[q].y);
                pa.z = f2bf(ra[q].z); pa.w = f2bf(ra[q].w);
                *reinterpret_cast<ushort4*>(&Asm[cur ^ 1][sr * ASTR + sf + q * 4]) = pa;
            }
            *reinterpret_cast<float4*>(&Wsm[cur ^ 1][tid * 8]) = rw;
            __syncthreads();
        }
    }

    #pragma unroll
    for (int cf = 0; cf < 4; ++cf) {
        const float bv = bias[c0 + wc * 64 + cf * 16 + lo];
        #pragma unroll
        for (int fm = 0; fm < 4; ++fm)
            #pragma unroll
            for (int j = 0; j < 4; ++j)
                X[(size_t)(n0 + wr * 64 + fm * 16 + hi * 4 + j) * D_OUT
                  + c0 + wc * 64 + cf * 16 + lo] = acc[fm][cf][j] + bv;
    }
}

// ============ Kernel 2: soft quantization head — 256 rows/block, in-register pa ============
// Block = (book b, 256 rows), 512 threads; wave w: rows w*32..+31 in 2 x 16-row iters
// vs ALL 256 m. xc = mfma(Cb, X^T): lane (lo,hi) holds p[x-row lo][m=16*mf+4*hi+j].
// Z GEMM's pa built IN-LANE from qa (packB m-order == qa layout). One barrier.
// X loads issued upfront with NT hint (each line read exactly once -> evict-first
// protects codebook/packW L2 set) and RETIRED into xf before the MFMA region.
// Z stores non-temporal (r12, -14 us).
__global__ __launch_bounds__(512, 4) void quant_head(
        const float* __restrict__ X, const unsigned short* __restrict__ packA,
        const unsigned short* __restrict__ packB, const float* __restrict__ nc2g,
        float* __restrict__ Z) {
    __shared__ __attribute__((aligned(16))) unsigned short cbA[16384];
    __shared__ __attribute__((aligned(16))) unsigned short cbB[16384];
    __shared__ float nc2s[256];

    const int tid  = threadIdx.x;
    const int bid  = blockIdx.x;
    // co-XCD grouping: 8 books of the same row range sit consecutively on ONE XCD
    const int xcd = bid & 7;
    const int idx = bid >> 3;            // 0..255 per XCD
    const int b   = idx & 7;
    const int n0  = (xcd * 32 + (idx >> 3)) * 256;
    const int lane = tid & 63;
    const int w    = tid >> 6;
    const int lo = lane & 15, hi = lane >> 4;

    // ---- X loads for both halves first (HBM/L3 latency starts earliest; NT hint) ----
    f32x4 rx[2][4];
    #pragma unroll
    for (int h = 0; h < 2; ++h) {
        const float* xp = X + (size_t)(n0 + w * 32 + h * 16 + lo) * D_OUT + b * 64 + hi * 8;
        rx[h][0] = __builtin_nontemporal_load(reinterpret_cast<const f32x4*>(xp));
        rx[h][1] = __builtin_nontemporal_load(reinterpret_cast<const f32x4*>(xp + 4));
        rx[h][2] = __builtin_nontemporal_load(reinterpret_cast<const f32x4*>(xp + 32));
        rx[h][3] = __builtin_nontemporal_load(reinterpret_cast<const f32x4*>(xp + 36));
    }

    // ---- stage codebook frags + nc2 into LDS ----
    {
        const float4* gA = reinterpret_cast<const float4*>(packA + (size_t)b * 16384);
        const float4* gB = reinterpret_cast<const float4*>(packB + (size_t)b * 16384);
        float4* sA = reinterpret_cast<float4*>(cbA);
        float4* sB = reinterpret_cast<float4*>(cbB);
        #pragma unroll
        for (int it = 0; it < 4; ++it) {
            sA[it * 512 + tid] = gA[it * 512 + tid];
            sB[it * 512 + tid] = gB[it * 512 + tid];
        }
        if (tid < 256) nc2s[tid] = nc2g[b * 256 + tid];
    }

    // ---- convert X to bf16 B-frags while staging lands (retires rx) ----
    short8 xf[2][2];   // [half][ks]
    #pragma unroll
    for (int h = 0; h < 2; ++h)
        #pragma unroll
        for (int ks = 0; ks < 2; ++ks) {
            const f32x4 v0 = rx[h][ks * 2];
            const f32x4 v1 = rx[h][ks * 2 + 1];
            short8 t;
            t[0] = (short)f2bf(v0[0]); t[1] = (short)f2bf(v0[1]);
            t[2] = (short)f2bf(v0[2]); t[3] = (short)f2bf(v0[3]);
            t[4] = (short)f2bf(v1[0]); t[5] = (short)f2bf(v1[1]);
            t[6] = (short)f2bf(v1[2]); t[7] = (short)f2bf(v1[3]);
            xf[h][ks] = t;
        }

    __syncthreads();   // codebook + nc2 staged

    const float S2 = 2.0f * TAU * LOG2E;
    for (int h = 0; h < 2; ++h) {
        // ---- xc MFMA: 16 rows x 256 m ----
        f32x4 qa[16];
        #pragma unroll
        for (int mf = 0; mf < 16; ++mf) qa[mf] = (f32x4){0.f, 0.f, 0.f, 0.f};
        #pragma unroll
        for (int ks = 0; ks < 2; ++ks)
            #pragma unroll
            for (int mf = 0; mf < 16; ++mf) {
                const short8 cfr = *reinterpret_cast<const short8*>(
                    &cbA[((ks * 16 + mf) * 64 + lane) * 8]);
                qa[mf] = __builtin_amdgcn_mfma_f32_16x16x32_bf16(
                    cfr, xf[h][ks], qa[mf], 0, 0, 0);
            }

        // ---- softmax (exp2 domain, in-lane, unnormalized p kept in qa) ----
        float s = 0.f;
        #pragma unroll
        for (int mf = 0; mf < 16; ++mf) {
            const f32x4 nv = *reinterpret_cast<const f32x4*>(&nc2s[mf * 16 + hi * 4]);
            const float p0 = exp2f(fmaf(qa[mf][0], S2, nv[0]));
            const float p1 = exp2f(fmaf(qa[mf][1], S2, nv[1]));
            const float p2 = exp2f(fmaf(qa[mf][2], S2, nv[2]));
            const float p3 = exp2f(fmaf(qa[mf][3], S2, nv[3]));
            qa[mf][0] = p0; qa[mf][1] = p1; qa[mf][2] = p2; qa[mf][3] = p3;
            s += (p0 + p1) + (p2 + p3);
        }
        s += __shfl_xor(s, 16, 64);
        s += __shfl_xor(s, 32, 64);
        const float inv = 1.0f / s;            // full 256-sum for this half's row `lo`

        // ---- Z = p @ Cb : pa built in-lane (packB m-order == qa layout) ----
        f32x4 acc2[4];
        #pragma unroll
        for (int n2 = 0; n2 < 4; ++n2) acc2[n2] = (f32x4){0.f, 0.f, 0.f, 0.f};
        #pragma unroll
        for (int ks2 = 0; ks2 < 8; ++ks2) {
            short8 pa;
            pa[0] = (short)f2bf(qa[2 * ks2][0]);     pa[1] = (short)f2bf(qa[2 * ks2][1]);
            pa[2] = (short)f2bf(qa[2 * ks2][2]);     pa[3] = (short)f2bf(qa[2 * ks2][3]);
            pa[4] = (short)f2bf(qa[2 * ks2 + 1][0]); pa[5] = (short)f2bf(qa[2 * ks2 + 1][1]);
            pa[6] = (short)f2bf(qa[2 * ks2 + 1][2]); pa[7] = (short)f2bf(qa[2 * ks2 + 1][3]);
            #pragma unroll
            for (int n2 = 0; n2 < 4; ++n2) {
                const short8 bv = *reinterpret_cast<const short8*>(
                    &cbB[((ks2 * 4 + n2) * 64 + lane) * 8]);
                acc2[n2] = __builtin_amdgcn_mfma_f32_16x16x32_bf16(pa, bv, acc2[n2], 0, 0, 0);
            }
        }

        float invr[4];
        #pragma unroll
        for (int j = 0; j < 4; ++j) invr[j] = __shfl(inv, hi * 4 + j, 64);
        #pragma unroll
        for (int n2 = 0; n2 < 4; ++n2)
            #pragma unroll
            for (int j = 0; j < 4; ++j)
                __builtin_nontemporal_store(
                    acc2[n2][j] * invr[j],
                    &Z[(size_t)(n0 + w * 32 + h * 16 + hi * 4 + j) * D_OUT
                       + b * 64 + n2 * 16 + lo]);
    }
}

// ============ launch ============
extern "C" void kernel_launch(void* const* d_in, const int* in_sizes, int n_in,
                              void* d_out, int out_size, void* d_ws, size_t ws_size,
                              hipStream_t stream) {
    const float* x = (const float*)d_in[0];
    const float* W = (const float*)d_in[1];
    const float* b = (const float*)d_in[2];
    const float* C = (const float*)d_in[3];

    float* X = (float*)d_out;                      // output 0: [65536, 512]
    float* Z = X + (size_t)N_ROWS * D_OUT;         // output 1: [65536, 512]

    unsigned short* packA = (unsigned short*)d_ws;          // 131072 bf16 = 256 KB
    unsigned short* packB = packA + 131072;                 // 131072 bf16 = 256 KB
    unsigned short* packW = packB + 131072;                 // 262144 bf16 = 512 KB
    float*          nc2g  = (float*)(packW + 262144);       // 2048 fp32  =   8 KB

    prep_codebook<<<dim3(2056), dim3(256), 0, stream>>>(C, W, packA, packB, packW, nc2g);
    gemm_fc<<<dim3(1024), dim3(512), 0, stream>>>(x, packW, b, X);
    quant_head<<<dim3(N_BOOKS * (N_ROWS / 256)), dim3(512), 0, stream>>>(
        X, packA, packB, nc2g, Z);
}